// Round 1
// baseline (539.363 us; speedup 1.0000x reference)
//
#include <hip/hip_runtime.h>
#include <math.h>

#define NN 64
#define CC 64
#define TT 128
#define VV 25
#define NSK 3
#define G8 8

// ---- workspace layout (float offsets) ----
#define OFF_XMEAN  0          // 64*64*25 = 102400
#define OFF_A12    102400     // 64*6*25  = 9600
#define OFF_ATT2   112000     // 64*25*25 = 40000
#define OFF_ATT    152000     // 64*36    = 2304
#define OFF_X1GCN  154304     // 64*8*128*6 = 393216
#define OFF_Y      547520     // 393216
#define OFF_A12L   940736     // 9600
#define OFF_W2EFF  950336     // 192*64 = 12288
#define OFF_B2EFF  962624     // 192
#define OFF_XMSUM  962816     // 64*6
#define OFF_YSUM   963200     // 64*6
#define OFF_Y1SUM  963584     // 64*25
#define OFF_QSUM   965184     // 64*64
#define OFF_Q2SUM  969280     // 64*64
#define OFF_ALPHA  973376     // 64*64
#define OFF_BETA   977472     // 64
#define ACC_START  OFF_XMSUM
#define ACC_LEN    (OFF_ALPHA - OFF_XMSUM)   // 10560 floats to zero

// K1: xmean[n,c,v] = mean_t x[n,c,t,v].  grid=4096 (n*c), block=64 (t)
__global__ __launch_bounds__(64) void k_xmean(const float* __restrict__ x, float* __restrict__ xmean){
  int nc = blockIdx.x;
  const float* p = x + (size_t)nc*TT*VV;
  float acc[VV];
  #pragma unroll
  for (int v=0;v<VV;++v) acc[v]=0.f;
  for (int t = threadIdx.x; t < TT; t += 64){
    const float* row = p + t*VV;
    #pragma unroll
    for (int v=0; v<VV; ++v) acc[v] += row[v];
  }
  #pragma unroll
  for (int v=0; v<VV; ++v){
    float a = acc[v];
    #pragma unroll
    for (int off=32; off; off>>=1) a += __shfl_down(a, off, 64);
    acc[v]=a;
  }
  if (threadIdx.x==0){
    #pragma unroll
    for (int v=0;v<VV;++v) xmean[nc*VV+v] = acc[v]*(1.f/TT);
  }
}

// W2eff = W2@Ws, b2eff = W2@bs + b2.  grid=192, block=64
__global__ __launch_bounds__(64) void k_w2eff(const float* __restrict__ W2, const float* __restrict__ Ws,
    const float* __restrict__ bs, const float* __restrict__ b2,
    float* __restrict__ W2eff, float* __restrict__ b2eff){
  int o = blockIdx.x, cc = threadIdx.x;
  float s = 0.f, sb = 0.f;
  for (int c1=0;c1<CC;++c1){ float w = W2[o*CC+c1]; s += w*Ws[c1*CC+cc]; sb += w*bs[c1]; }
  W2eff[o*CC+cc] = s;
  if (cc==0) b2eff[o] = sb + b2[o];
}

// K2: A12[n,q,v], att2[n,v,w] from xmean.  grid=64 (n), block=64
__global__ __launch_bounds__(64) void k_attn1(const float* __restrict__ xmean,
    const float* __restrict__ Wp, const float* __restrict__ bp,
    const float* __restrict__ Ws, const float* __restrict__ bs,
    const float* __restrict__ w_t1, const float* __restrict__ w_t2,
    const float* __restrict__ w_tw11, const float* __restrict__ w_tw21,
    float* __restrict__ A12, float* __restrict__ att2){
  int n = blockIdx.x, tid = threadIdx.x;
  __shared__ float wpbar[CC], wsbar[CC];
  __shared__ float a2pre[VV], a2[VV], r1[VV], r2[VV], a1[6];
  {
    float s=0.f, s2=0.f;
    for (int o=0;o<G8;++o) s += Wp[o*CC+tid];
    for (int o=0;o<CC;++o) s2 += Ws[o*CC+tid];
    wpbar[tid]=s*(1.f/G8); wsbar[tid]=s2*(1.f/CC);
  }
  __syncthreads();
  float bpbar=0.f, bsbar=0.f;
  for (int o=0;o<G8;++o) bpbar += bp[o];
  bpbar *= (1.f/G8);
  for (int o=0;o<CC;++o) bsbar += bs[o];
  bsbar *= (1.f/CC);
  if (tid < VV){
    float s1=0.f, s2=0.f;
    const float* xm = xmean + n*CC*VV + tid;
    for (int c=0;c<CC;++c){ float xv = xm[c*VV]; s1 += xv*wpbar[c]; s2 += xv*wsbar[c]; }
    float ap = s1 + bpbar, xm2v = s2 + bsbar;
    a2pre[tid] = ap;
    a2[tid] = fmaxf(0.f, w_t2[0]*ap);
    r1[tid] = fmaxf(0.f, w_tw11[0]*xm2v);
    r2[tid] = fmaxf(0.f, w_tw21[0]*xm2v);
  }
  __syncthreads();
  if (tid < 6){
    const int J[6]={3,20,7,11,14,18};
    a1[tid] = fmaxf(0.f, w_t1[0]*a2pre[J[tid]]);
  }
  __syncthreads();
  if (tid < VV){
    // A12: softmax over q for each v
    float m=-1e30f;
    #pragma unroll
    for (int q=0;q<6;++q) m = fmaxf(m, a1[q]*a2[tid]);
    float e[6]; float s=0.f;
    #pragma unroll
    for (int q=0;q<6;++q){ e[q]=__expf(a1[q]*a2[tid]-m); s+=e[q]; }
    float inv=1.f/s;
    #pragma unroll
    for (int q=0;q<6;++q) A12[(n*6+q)*VV+tid] = e[q]*inv;
    // att2: softmax over v for each w=tid
    float m2=-1e30f;
    for (int v=0;v<VV;++v) m2 = fmaxf(m2, r1[v]*r2[tid]);
    float s2=0.f;
    for (int v=0;v<VV;++v) s2 += __expf(r1[v]*r2[tid]-m2);
    float inv2=1.f/s2;
    for (int v=0;v<VV;++v) att2[(n*VV+v)*VV+tid] = __expf(r1[v]*r2[tid]-m2)*inv2;
  }
}

// K3: x1 -> x1_GCN (+ xmsum partials).  grid=64*16, block=256, t-tile=8
__global__ __launch_bounds__(256) void k_x1gcn(const float* __restrict__ x,
    const float* __restrict__ Wp, const float* __restrict__ bp,
    const float* __restrict__ A12, float* __restrict__ x1gcn, float* __restrict__ xmsum){
  __shared__ float xs[CC][200];
  __shared__ float x1s[G8][200];
  __shared__ float A12s[6][VV];
  __shared__ float Wps[G8][CC];
  __shared__ float qb[6];
  int n = blockIdx.x >> 4;
  int t0 = (blockIdx.x & 15) * 8;
  int tid = threadIdx.x;
  if (tid < 6*VV) A12s[tid/VV][tid%VV] = A12[n*6*VV + tid];
  if (tid >= 6*VV && tid < 6*VV+6) qb[tid - 6*VV] = 0.f;
  for (int f=tid; f<G8*CC; f+=256) Wps[f>>6][f&63] = Wp[f];
  const float* xb = x + (size_t)n*CC*TT*VV + t0*VV;
  for (int f=tid; f<CC*200; f+=256){
    int c = f/200, j = f - c*200;
    xs[c][j] = xb[c*TT*VV + j];
  }
  __syncthreads();
  for (int f=tid; f<G8*200; f+=256){
    int o = f/200, j = f - o*200;
    float s = bp[o];
    #pragma unroll 16
    for (int c=0;c<CC;++c) s += xs[c][j]*Wps[o][c];
    x1s[o][j] = s;
  }
  __syncthreads();
  float* xg = x1gcn + ((size_t)n*G8*TT + t0)*6;
  for (int f=tid; f<G8*48; f+=256){
    int o=f/48, r=f-o*48, tl=r/6, q=r-tl*6;
    const float* xr = &x1s[o][tl*VV];
    float s=0.f;
    #pragma unroll
    for (int v=0;v<VV;++v) s += xr[v]*A12s[q][v];
    xg[o*TT*6 + tl*6 + q] = s;
    atomicAdd(&qb[q], s);
  }
  __syncthreads();
  if (tid<6) atomicAdd(&xmsum[n*6+tid], qb[tid]);
}

// K4: att[n,i,j] from xmsum.  grid=64, block=64
__global__ __launch_bounds__(64) void k_att(const float* __restrict__ xmsum,
    const float* __restrict__ w_tw1, const float* __restrict__ w_tw2, float* __restrict__ att){
  int n=blockIdx.x, tid=threadIdx.x;
  __shared__ float aa[6], bb[6];
  if (tid<6){
    float xm = xmsum[n*6+tid]*(1.f/(G8*TT));
    aa[tid]=fmaxf(0.f, w_tw1[0]*xm);
    bb[tid]=fmaxf(0.f, w_tw2[0]*xm);
  }
  __syncthreads();
  if (tid<6){
    float m=-1e30f;
    #pragma unroll
    for(int i=0;i<6;++i) m=fmaxf(m, aa[i]*bb[tid]);
    float e[6]; float s=0.f;
    #pragma unroll
    for(int i=0;i<6;++i){ e[i]=__expf(aa[i]*bb[tid]-m); s+=e[i]; }
    float inv=1.f/s;
    #pragma unroll
    for(int i=0;i<6;++i) att[(n*6+i)*6+tid]=e[i]*inv;
  }
}

// K5: m = conv(x1_GCN,W1); y = einsum(m, 0.5*att + nlp) (+ ysum).  grid=64*4, block=256, t-tile=32
__global__ __launch_bounds__(256) void k_y(const float* __restrict__ x1gcn,
    const float* __restrict__ W1, const float* __restrict__ b1,
    const float* __restrict__ att, const float* __restrict__ Dpap, const float* __restrict__ pa,
    float* __restrict__ y, float* __restrict__ ysum){
  __shared__ float xg[G8][192];
  __shared__ float ms[24][192];
  __shared__ float F[NSK][G8][36];
  __shared__ float W1s[24][G8];
  __shared__ float ysb[6];
  int n = blockIdx.x >> 2;
  int t0 = (blockIdx.x & 3) * 32;
  int tid = threadIdx.x;
  float* Ff = &F[0][0][0];
  for (int f=tid; f<NSK*G8*36; f+=256){
    int ij = f % 36;
    Ff[f] = 0.5f*att[n*36+ij] + Dpap[f] + pa[f];
  }
  if (tid < 24*G8) W1s[tid/G8][tid%G8] = W1[tid];
  if (tid < 6) ysb[tid] = 0.f;
  const float* xgb = x1gcn + ((size_t)n*G8*TT + t0)*6;
  for (int f=tid; f<G8*192; f+=256){
    int o=f/192, j=f-o*192;
    xg[o][j] = xgb[o*TT*6 + j];
  }
  __syncthreads();
  for (int f=tid; f<24*192; f+=256){
    int o=f/192, j=f-o*192;
    float s = b1[o];
    #pragma unroll
    for (int c=0;c<G8;++c) s += xg[c][j]*W1s[o][c];
    ms[o][j] = s;
  }
  __syncthreads();
  float* yb = y + ((size_t)n*G8*TT + t0)*6;
  for (int f=tid; f<G8*192; f+=256){
    int c=f/192, r=f-c*192, tl=r/6, w=r-tl*6;
    float s=0.f;
    #pragma unroll
    for (int k=0;k<NSK;++k){
      #pragma unroll
      for (int v=0;v<6;++v) s += ms[k*G8+c][tl*6+v]*F[k][c][v*6+w];
    }
    yb[c*TT*6 + r] = s;
    atomicAdd(&ysb[w], s);
  }
  __syncthreads();
  if (tid<6) atomicAdd(&ysum[n*6+tid], ysb[tid]);
}

// K7: y1[n,c,t,w] = sum_{k,v} (x . W2eff + b2eff) * (0.5*att2 + A1buf + DecA)  -> d_out (+ y1sum)
// grid = 64*32 (t-tile=4), block=256: lane=c, wave=tl
__global__ __launch_bounds__(256) void k_y1(const float* __restrict__ x,
    const float* __restrict__ W2eff, const float* __restrict__ b2eff,
    const float* __restrict__ att2, const float* __restrict__ A1buf, const float* __restrict__ DecA,
    float* __restrict__ y1, float* __restrict__ y1sum){
  __shared__ __align__(16) float xT[100][68];   // [tv][c], stride 68 (16B-aligned rows, 8-way write conflict only)
  __shared__ float E[G8][VV*VV];
  __shared__ float y1sb[VV];
  int n = blockIdx.x >> 5;
  int t0 = (blockIdx.x & 31) * 4;
  int tid = threadIdx.x;
  int c = tid & 63;
  int tl = tid >> 6;
  const float* xb = x + (size_t)n*CC*TT*VV + t0*VV;
  for (int f = tid; f < CC*100; f += 256){
    int cc = f/100, tv = f - cc*100;
    xT[tv][cc] = xb[cc*TT*VV + tv];
  }
  if (tid < VV) y1sb[tid] = 0.f;
  float acc[VV];
  #pragma unroll
  for (int w=0;w<VV;++w) acc[w]=0.f;
  float* Ef = &E[0][0];
  for (int k=0;k<NSK;++k){
    __syncthreads();   // k=0: xT ready; k>0: prior E reads done
    for (int f=tid; f<G8*VV*VV; f+=256){
      Ef[f] = 0.5f*att2[n*VV*VV + (f % (VV*VV))] + A1buf[k*G8*VV*VV + f] + DecA[k*G8*VV*VV + f];
    }
    float w2r[CC];
    const float4* wr = (const float4*)&W2eff[(k*CC + c)*CC];
    #pragma unroll
    for (int j=0;j<16;++j){
      float4 t4 = wr[j];
      w2r[4*j+0]=t4.x; w2r[4*j+1]=t4.y; w2r[4*j+2]=t4.z; w2r[4*j+3]=t4.w;
    }
    float bk = b2eff[k*CC + c];
    __syncthreads();
    const float* Eg = &E[c & 7][0];
    for (int v=0; v<VV; ++v){
      const float4* xr = (const float4*)&xT[tl*VV + v][0];  // wave-uniform -> broadcast b128
      float m2 = bk;
      #pragma unroll
      for (int j=0;j<16;++j){
        float4 xv = xr[j];
        m2 += xv.x*w2r[4*j+0] + xv.y*w2r[4*j+1] + xv.z*w2r[4*j+2] + xv.w*w2r[4*j+3];
      }
      const float* Ev = Eg + v*VV;
      #pragma unroll
      for (int w=0;w<VV;++w) acc[w] += m2 * Ev[w];
    }
  }
  float* yb = y1 + (size_t)n*CC*TT*VV + t0*VV;
  #pragma unroll
  for (int w=0;w<VV;++w) yb[c*TT*VV + tl*VV + w] = acc[w];
  #pragma unroll
  for (int w=0;w<VV;++w){
    float a = acc[w];
    #pragma unroll
    for (int off=32; off; off>>=1) a += __shfl_down(a, off, 64);
    if ((tid & 63)==0) atomicAdd(&y1sb[w], a);
  }
  __syncthreads();
  if (tid < VV) atomicAdd(&y1sum[n*VV+tid], y1sb[tid]);
}

// K8: A12l from ysum/y1sum.  grid=64, block=64
__global__ __launch_bounds__(64) void k_a12l(const float* __restrict__ ysum, const float* __restrict__ y1sum,
    const float* __restrict__ w_s1, const float* __restrict__ w_s2, float* __restrict__ A12l){
  int n=blockIdx.x, tid=threadIdx.x;
  __shared__ float a1l[6], a2l[VV];
  if (tid<6) a1l[tid] = fmaxf(0.f, w_s1[0]*ysum[n*6+tid]*(1.f/(G8*TT)));
  if (tid<VV) a2l[tid] = fmaxf(0.f, w_s2[0]*y1sum[n*VV+tid]*(1.f/(CC*TT)));
  __syncthreads();
  if (tid<VV){
    float m=-1e30f;
    #pragma unroll
    for(int q=0;q<6;++q) m=fmaxf(m, a1l[q]*a2l[tid]);
    float e[6]; float s=0.f;
    #pragma unroll
    for(int q=0;q<6;++q){ e[q]=__expf(a1l[q]*a2l[tid]-m); s+=e[q]; }
    float inv=1.f/s;
    #pragma unroll
    for(int q=0;q<6;++q) A12l[(n*6+q)*VV+tid] = e[q]*inv;
  }
}

// K9: y' = 0.5*conv(y@A12l, We) + y1 (in-place on d_out), accumulate q, q2.
// grid = 64*32 (t-tile=4), block=256: lane=c, wave=tl
__global__ __launch_bounds__(256) void k_yprime(const float* __restrict__ y,
    const float* __restrict__ A12l, const float* __restrict__ We, const float* __restrict__ be,
    float* __restrict__ yp, float* __restrict__ qsum, float* __restrict__ q2sum){
  __shared__ float ys[G8][24];
  __shared__ float Al[6][VV];
  __shared__ float WesT[G8][CC];
  __shared__ float z[G8][4][VV];
  __shared__ float qb[CC], q2b[CC];
  int n = blockIdx.x >> 5;
  int t0 = (blockIdx.x & 31) * 4;
  int tid = threadIdx.x;
  int c = tid & 63, tl = tid >> 6;
  if (tid < 6*VV) Al[tid/VV][tid%VV] = A12l[n*6*VV + tid];
  for (int f=tid; f<CC*G8; f+=256) WesT[f&7][f>>3] = We[f];
  if (tid < G8*24){ int o=tid/24, j=tid-o*24; ys[o][j] = y[((size_t)(n*G8+o)*TT + t0)*6 + j]; }
  if (tid < CC){ qb[tid]=0.f; q2b[tid]=0.f; }
  __syncthreads();
  for (int f=tid; f<G8*4*VV; f+=256){
    int o=f/100, r=f-o*100, t=r/VV, w=r-t*VV;
    float s=0.f;
    #pragma unroll
    for (int v=0;v<6;++v) s += ys[o][t*6+v]*Al[v][w];
    z[o][t][w]=s;
  }
  __syncthreads();
  float* yb = yp + ((size_t)n*CC + c)*TT*VV + (t0+tl)*VV;
  float qs=0.f, q2s=0.f;
  float bec = be[c];
  #pragma unroll
  for (int w=0;w<VV;++w){
    float s = bec;
    #pragma unroll
    for (int o=0;o<G8;++o) s += z[o][tl][w]*WesT[o][c];
    float val = 0.5f*s + yb[w];
    yb[w] = val;
    qs += val; q2s += val*val;
  }
  atomicAdd(&qb[c], qs); atomicAdd(&q2b[c], q2s);
  __syncthreads();
  if (tid < CC){ atomicAdd(&qsum[n*CC+tid], qb[tid]); atomicAdd(&q2sum[n*CC+tid], q2b[tid]); }
}

// K10: gate + BN -> alpha[n,c], beta[c].  single block
__global__ __launch_bounds__(256) void k_bnparams(const float* __restrict__ qsum, const float* __restrict__ q2sum,
    const float* __restrict__ k_ca, const float* __restrict__ bn_g, const float* __restrict__ bn_b,
    float* __restrict__ alpha, float* __restrict__ beta){
  __shared__ float gg[NN*CC];
  __shared__ float qm[NN*CC];
  __shared__ float scale_s[CC];
  int tid = threadIdx.x;
  for (int f=tid; f<NN*CC; f+=256) qm[f] = qsum[f]*(1.f/(TT*VV));
  __syncthreads();
  float k0=k_ca[0], k1=k_ca[1], k2=k_ca[2];
  for (int f=tid; f<NN*CC; f+=256){
    int cch = f & 63;
    float qm1 = cch>0  ? qm[f-1] : 0.f;
    float qp1 = cch<63 ? qm[f+1] : 0.f;
    float qc = k0*qm1 + k1*qm[f] + k2*qp1;
    gg[f] = 1.f + 1.f/(1.f+__expf(-qc));
  }
  __syncthreads();
  if (tid < CC){
    float mu=0.f, e2=0.f;
    for (int nn=0; nn<NN; ++nn){
      float g = gg[nn*CC+tid];
      mu += g * qm[nn*CC+tid];
      e2 += g*g*q2sum[nn*CC+tid];
    }
    mu *= (1.f/NN);
    e2 *= (1.f/(NN*TT*VV));
    float var = e2 - mu*mu;
    float sc = bn_g[tid]*rsqrtf(var+1e-5f);
    scale_s[tid]=sc;
    beta[tid] = bn_b[tid] - mu*sc;
  }
  __syncthreads();
  for (int f=tid; f<NN*CC; f+=256) alpha[f] = gg[f]*scale_s[f & 63];
}

// K11: out = relu(y'*alpha + beta + x), in-place on d_out.  grid=12800, block=256 (1 float4/thread)
__global__ __launch_bounds__(256) void k_final(const float* __restrict__ x,
    const float* __restrict__ alpha, const float* __restrict__ beta,
    float* __restrict__ out){
  int i = blockIdx.x*256 + threadIdx.x;
  const float4* x4 = (const float4*)x;
  float4* o4 = (float4*)out;
  float4 xv = x4[i];
  float4 yv = o4[i];
  int nc = i / 800;              // (T*V)/4 = 800, quads never straddle (n,c)
  float a = alpha[nc], b = beta[nc & 63];
  float4 r;
  r.x = fmaxf(0.f, yv.x*a + b + xv.x);
  r.y = fmaxf(0.f, yv.y*a + b + xv.y);
  r.z = fmaxf(0.f, yv.z*a + b + xv.z);
  r.w = fmaxf(0.f, yv.w*a + b + xv.w);
  o4[i] = r;
}

extern "C" void kernel_launch(void* const* d_in, const int* in_sizes, int n_in,
                              void* d_out, int out_size, void* d_ws, size_t ws_size,
                              hipStream_t stream) {
  const float* x    = (const float*)d_in[0];
  const float* Dpap = (const float*)d_in[1];
  const float* pa   = (const float*)d_in[2];
  const float* DecA = (const float*)d_in[3];
  const float* A1buf= (const float*)d_in[4];
  const float* Wp   = (const float*)d_in[5];
  const float* bp   = (const float*)d_in[6];
  const float* Ws   = (const float*)d_in[7];
  const float* bs   = (const float*)d_in[8];
  const float* W1   = (const float*)d_in[9];
  const float* b1   = (const float*)d_in[10];
  const float* W2   = (const float*)d_in[11];
  const float* b2   = (const float*)d_in[12];
  const float* We   = (const float*)d_in[13];
  const float* be   = (const float*)d_in[14];
  const float* w_t1 = (const float*)d_in[15];
  const float* w_t2 = (const float*)d_in[16];
  const float* w_tw1  = (const float*)d_in[17];
  const float* w_tw2  = (const float*)d_in[18];
  const float* w_tw11 = (const float*)d_in[19];
  const float* w_tw21 = (const float*)d_in[20];
  const float* w_s1 = (const float*)d_in[21];
  const float* w_s2 = (const float*)d_in[22];
  const float* k_ca = (const float*)d_in[23];
  const float* bn_g = (const float*)d_in[24];
  const float* bn_b = (const float*)d_in[25];
  float* out = (float*)d_out;
  float* ws  = (float*)d_ws;

  float* xmean = ws + OFF_XMEAN;
  float* A12   = ws + OFF_A12;
  float* att2  = ws + OFF_ATT2;
  float* att   = ws + OFF_ATT;
  float* x1gcn = ws + OFF_X1GCN;
  float* yv    = ws + OFF_Y;
  float* A12l  = ws + OFF_A12L;
  float* w2eff = ws + OFF_W2EFF;
  float* b2eff = ws + OFF_B2EFF;
  float* xmsum = ws + OFF_XMSUM;
  float* ysum  = ws + OFF_YSUM;
  float* y1sum = ws + OFF_Y1SUM;
  float* qsum  = ws + OFF_QSUM;
  float* q2sum = ws + OFF_Q2SUM;
  float* alpha = ws + OFF_ALPHA;
  float* beta  = ws + OFF_BETA;

  hipMemsetAsync(ws + ACC_START, 0, ACC_LEN*sizeof(float), stream);

  k_w2eff<<<192, 64, 0, stream>>>(W2, Ws, bs, b2, w2eff, b2eff);
  k_xmean<<<NN*CC, 64, 0, stream>>>(x, xmean);
  k_attn1<<<NN, 64, 0, stream>>>(xmean, Wp, bp, Ws, bs, w_t1, w_t2, w_tw11, w_tw21, A12, att2);
  k_y1<<<NN*32, 256, 0, stream>>>(x, w2eff, b2eff, att2, A1buf, DecA, out, y1sum);
  k_x1gcn<<<NN*16, 256, 0, stream>>>(x, Wp, bp, A12, x1gcn, xmsum);
  k_att<<<NN, 64, 0, stream>>>(xmsum, w_tw1, w_tw2, att);
  k_y<<<NN*4, 256, 0, stream>>>(x1gcn, W1, b1, att, Dpap, pa, yv, ysum);
  k_a12l<<<NN, 64, 0, stream>>>(ysum, y1sum, w_s1, w_s2, A12l);
  k_yprime<<<NN*32, 256, 0, stream>>>(yv, A12l, We, be, out, qsum, q2sum);
  k_bnparams<<<1, 256, 0, stream>>>(qsum, q2sum, k_ca, bn_g, bn_b, alpha, beta);
  k_final<<<(NN*CC*TT*VV)/1024, 256, 0, stream>>>(x, alpha, beta, out);
}